// Round 1
// baseline (695.908 us; speedup 1.0000x reference)
//
#include <hip/hip_runtime.h>
#include <float.h>

#define Nn 32
#define Ll 2048
#define Cc 128
#define NTILES 32
#define TILE 64                 // Ll / NTILES
#define OUTC 1172               // 3*384 + 20
#define NLC (Nn * Ll * Cc)      // 8388608
#define OUT_ELEMS ((size_t)Nn * Ll * OUTC)  // 76808192
#define AGG (3 * Nn * NTILES * Cc)          // 393216

// ---------------- Phase 1: per-tile aggregates ----------------
__global__ void k_agg(const float* __restrict__ x0, const float* __restrict__ x1,
                      const float* __restrict__ x2,
                      float* __restrict__ aggMax, int* __restrict__ aggIdx,
                      float* __restrict__ aggSum) {
    int b = blockIdx.x;           // 0..3071
    int inp = b >> 10;            // / 1024
    int rem = b & 1023;
    int n = rem >> 5;             // / 32
    int tile = rem & 31;
    int c = threadIdx.x;          // 0..127
    const float* x = (inp == 0) ? x0 : ((inp == 1) ? x1 : x2);
    int t0 = tile * TILE;
    const float* p = x + ((size_t)n * Ll + t0) * Cc + c;

    float m = -FLT_MAX; int mi = 0; float s = 0.f;
#pragma unroll 4
    for (int t = 0; t < TILE; ++t) {
        float v = p[(size_t)t * Cc];
        s += v;
        if (v > m) { m = v; mi = t0 + t; }   // strict > : earlier index wins ties
    }
    int o = ((inp * Nn + n) * NTILES + tile) * Cc + c;
    aggMax[o] = m; aggIdx[o] = mi; aggSum[o] = s;
}

// ---------------- Phase 2: exclusive scan over tile aggregates (in place) ----------------
__global__ void k_scan_tiles(float* __restrict__ aggMax, int* __restrict__ aggIdx,
                             float* __restrict__ aggSum) {
    int tid = blockIdx.x * blockDim.x + threadIdx.x;   // 0..12287
    if (tid >= 3 * Nn * Cc) return;
    int inp = tid / (Nn * Cc);
    int rem = tid - inp * (Nn * Cc);
    int n = rem >> 7;             // / Cc
    int c = rem & 127;
    int base = ((inp * Nn + n) * NTILES) * Cc + c;

    float m = -FLT_MAX; int mi = 0; float s = 0.f;
    for (int j = 0; j < NTILES; ++j) {
        int o = base + j * Cc;
        float am = aggMax[o]; int ai = aggIdx[o]; float as = aggSum[o];
        aggMax[o] = m; aggIdx[o] = mi; aggSum[o] = s;   // exclusive prefix
        if (am > m) { m = am; mi = ai; }
        s += as;
    }
}

// ---------------- Tiny MLP: d = relu(relu(dem@W1+b1)@W2+b2) ----------------
__global__ void k_mlp(const float* __restrict__ dem, const float* __restrict__ W1,
                      const float* __restrict__ b1, const float* __restrict__ W2,
                      const float* __restrict__ b2, float* __restrict__ dvals) {
    int n = threadIdx.x;
    if (n >= Nn) return;
    float h[40];
    float de[8];
#pragma unroll
    for (int k = 0; k < 8; ++k) de[k] = dem[n * 8 + k];
#pragma unroll
    for (int j = 0; j < 40; ++j) {
        float s = b1[j];
#pragma unroll
        for (int k = 0; k < 8; ++k) s += de[k] * W1[k * 40 + j];
        h[j] = fmaxf(s, 0.f);
    }
#pragma unroll
    for (int o = 0; o < 20; ++o) {
        float s = b2[o];
#pragma unroll
        for (int j = 0; j < 40; ++j) s += h[j] * W2[j * 20 + o];
        dvals[n * 20 + o] = fmaxf(s, 0.f);
    }
}

// ---------------- Phase 3: rescan with carry, write all outputs ----------------
__global__ void k_apply(const float* __restrict__ x0, const float* __restrict__ x1,
                        const float* __restrict__ x2,
                        const float* __restrict__ aggMax, const int* __restrict__ aggIdx,
                        const float* __restrict__ aggSum, const float* __restrict__ dvals,
                        float* __restrict__ out) {
    int b = blockIdx.x;
    int inp = b >> 10;
    int rem = b & 1023;
    int n = rem >> 5;
    int tile = rem & 31;
    int c = threadIdx.x;
    const float* x = (inp == 0) ? x0 : ((inp == 1) ? x1 : x2);
    int t0 = tile * TILE;

    int o = ((inp * Nn + n) * NTILES + tile) * Cc + c;
    float m = aggMax[o]; int mi = aggIdx[o]; float s = aggSum[o];   // carry-in (exclusive)

    const float* p = x + ((size_t)n * Ll + t0) * Cc + c;
    // out column layout: inp*384 + {0:pmax, 128:pavg, 256:psum}, then 1152..1171 = d
    float* orow = out + (size_t)n * Ll * OUTC + (size_t)t0 * OUTC + inp * 384 + c;
    float* inds = out + OUT_ELEMS + (size_t)inp * NLC + ((size_t)n * Ll + t0) * Cc + c;
    float* acts = out + OUT_ELEMS + 3 * (size_t)NLC + (size_t)inp * NLC + ((size_t)n * Ll + t0) * Cc + c;

    const float invL = 1.0f / (float)Ll;
#pragma unroll 4
    for (int tl = 0; tl < TILE; ++tl) {
        int t = t0 + tl;
        float v = p[(size_t)tl * Cc];
        s += v;
        if (v > m) { m = v; mi = t; }
        float cmax = m;
        bool haspad = (t < Ll - 1);
        float pmax = haspad ? fmaxf(cmax, 0.f) : cmax;
        int pidx = (haspad && cmax < 0.f) ? (t - (Ll - 1)) : mi;
        float pavg = s * invL;
        float psum = s / (float)(t + 1);

        size_t ro = (size_t)tl * OUTC;
        orow[ro] = pmax;
        orow[ro + 128] = pavg;
        orow[ro + 256] = psum;
        inds[(size_t)tl * Cc] = (float)pidx;
        acts[(size_t)tl * Cc] = pmax;
    }

    // broadcast the MLP output columns (once, via the inp==0 blocks)
    if (inp == 0) {
        float* dout = out + (size_t)n * Ll * OUTC + (size_t)t0 * OUTC + 1152;
        for (int idx = c; idx < TILE * 20; idx += 128) {
            int tl = idx / 20;
            int k = idx - tl * 20;
            dout[(size_t)tl * OUTC + k] = dvals[n * 20 + k];
        }
    }
}

extern "C" void kernel_launch(void* const* d_in, const int* in_sizes, int n_in,
                              void* d_out, int out_size, void* d_ws, size_t ws_size,
                              hipStream_t stream) {
    const float* x0  = (const float*)d_in[0];
    const float* x1  = (const float*)d_in[1];
    const float* x2  = (const float*)d_in[2];
    const float* dem = (const float*)d_in[3];
    const float* W1  = (const float*)d_in[4];
    const float* b1  = (const float*)d_in[5];
    const float* W2  = (const float*)d_in[6];
    const float* b2  = (const float*)d_in[7];
    float* out = (float*)d_out;

    char* ws = (char*)d_ws;
    float* aggMax = (float*)ws;
    int*   aggIdx = (int*)(ws + (size_t)AGG * 4);
    float* aggSum = (float*)(ws + 2 * (size_t)AGG * 4);
    float* dvals  = (float*)(ws + 3 * (size_t)AGG * 4);

    k_agg<<<dim3(3 * Nn * NTILES), dim3(Cc), 0, stream>>>(x0, x1, x2, aggMax, aggIdx, aggSum);
    k_scan_tiles<<<dim3(48), dim3(256), 0, stream>>>(aggMax, aggIdx, aggSum);
    k_mlp<<<dim3(1), dim3(64), 0, stream>>>(dem, W1, b1, W2, b2, dvals);
    k_apply<<<dim3(3 * Nn * NTILES), dim3(Cc), 0, stream>>>(x0, x1, x2, aggMax, aggIdx, aggSum, dvals, out);
}

// Round 2
// 671.296 us; speedup vs baseline: 1.0367x; 1.0367x over previous
//
#include <hip/hip_runtime.h>
#include <float.h>

#define Nn 32
#define Ll 2048
#define Cc 128
#define NTILES 64
#define TILE 32                 // Ll / NTILES
#define OUTC 1172               // 3*384 + 20
#define NLC (Nn * Ll * Cc)      // 8388608
#define OUT_ELEMS ((size_t)Nn * Ll * OUTC)  // 76808192
#define NUNITS (3 * Nn * NTILES)            // 6144
#define AGG (NUNITS * Cc)                   // 786432

typedef float  f4 __attribute__((ext_vector_type(4)));
typedef int    i4 __attribute__((ext_vector_type(4)));

// ---------------- Phase 1: per-tile aggregates (float4 lanes) ----------------
__global__ __launch_bounds__(256) void k_agg(
        const float* __restrict__ x0, const float* __restrict__ x1,
        const float* __restrict__ x2,
        f4* __restrict__ aggMax, i4* __restrict__ aggIdx, f4* __restrict__ aggSum) {
    int unit = blockIdx.x * 8 + (threadIdx.x >> 5);   // (inp, n, tile)
    int lane = threadIdx.x & 31;                      // c4 group: channels lane*4..lane*4+3
    int inp = unit >> 11;                             // / (Nn*NTILES)=2048
    int rem = unit & 2047;
    int n = rem >> 6;                                 // / NTILES
    int tile = rem & 63;
    const float* x = (inp == 0) ? x0 : ((inp == 1) ? x1 : x2);
    int t0 = tile * TILE;
    const f4* p = (const f4*)(x + ((size_t)n * Ll + t0) * Cc) + lane;

    f4 m = { -FLT_MAX, -FLT_MAX, -FLT_MAX, -FLT_MAX };
    i4 mi = { 0, 0, 0, 0 };
    f4 s = { 0.f, 0.f, 0.f, 0.f };
#pragma unroll 4
    for (int tl = 0; tl < TILE; ++tl) {
        f4 v = p[(size_t)tl * (Cc / 4)];
        int t = t0 + tl;
#pragma unroll
        for (int j = 0; j < 4; ++j) {
            s[j] += v[j];
            if (v[j] > m[j]) { m[j] = v[j]; mi[j] = t; }   // strict >: earlier wins ties
        }
    }
    int o = unit * (Cc / 4) + lane;
    aggMax[o] = m; aggIdx[o] = mi; aggSum[o] = s;
}

// ---------------- Phase 2: exclusive scan over tile aggregates (in place) ----------------
__global__ __launch_bounds__(256) void k_scan_tiles(
        float* __restrict__ aggMax, int* __restrict__ aggIdx, float* __restrict__ aggSum) {
    int tid = blockIdx.x * blockDim.x + threadIdx.x;   // 0..12287  (inp, n, c)
    if (tid >= 3 * Nn * Cc) return;
    int inp = tid / (Nn * Cc);
    int rem = tid - inp * (Nn * Cc);
    int n = rem >> 7;
    int c = rem & 127;
    int base = ((inp * Nn + n) * NTILES) * Cc + c;

    float m = -FLT_MAX; int mi = 0; float s = 0.f;
    for (int j = 0; j < NTILES; ++j) {
        int o = base + j * Cc;
        float am = aggMax[o]; int ai = aggIdx[o]; float as = aggSum[o];
        aggMax[o] = m; aggIdx[o] = mi; aggSum[o] = s;   // exclusive prefix
        if (am > m) { m = am; mi = ai; }
        s += as;
    }
}

// ---------------- Tiny MLP: d = relu(relu(dem@W1+b1)@W2+b2) ----------------
__global__ void k_mlp(const float* __restrict__ dem, const float* __restrict__ W1,
                      const float* __restrict__ b1, const float* __restrict__ W2,
                      const float* __restrict__ b2, float* __restrict__ dvals) {
    int n = threadIdx.x;
    if (n >= Nn) return;
    float h[40];
    float de[8];
#pragma unroll
    for (int k = 0; k < 8; ++k) de[k] = dem[n * 8 + k];
#pragma unroll
    for (int j = 0; j < 40; ++j) {
        float s = b1[j];
#pragma unroll
        for (int k = 0; k < 8; ++k) s += de[k] * W1[k * 40 + j];
        h[j] = fmaxf(s, 0.f);
    }
#pragma unroll
    for (int o = 0; o < 20; ++o) {
        float s = b2[o];
#pragma unroll
        for (int j = 0; j < 40; ++j) s += h[j] * W2[j * 20 + o];
        dvals[n * 20 + o] = fmaxf(s, 0.f);
    }
}

// ---------------- Phase 3: rescan with carry, float4 writes everywhere ----------------
__global__ __launch_bounds__(256) void k_apply(
        const float* __restrict__ x0, const float* __restrict__ x1,
        const float* __restrict__ x2,
        const f4* __restrict__ aggMax, const i4* __restrict__ aggIdx,
        const f4* __restrict__ aggSum, const float* __restrict__ dvals,
        float* __restrict__ out) {
    int unit = blockIdx.x * 8 + (threadIdx.x >> 5);
    int lane = threadIdx.x & 31;
    int inp = unit >> 11;
    int rem = unit & 2047;
    int n = rem >> 6;
    int tile = rem & 63;
    const float* x = (inp == 0) ? x0 : ((inp == 1) ? x1 : x2);
    int t0 = tile * TILE;

    int o = unit * (Cc / 4) + lane;
    f4 m = aggMax[o]; i4 mi = aggIdx[o]; f4 s = aggSum[o];   // carry-in (exclusive)

    const f4* p = (const f4*)(x + ((size_t)n * Ll + t0) * Cc) + lane;
    // out column layout per row: inp*384 + {0:pmax, 128:pavg, 256:psum}, then 1152..1171 = d
    f4* omax = (f4*)(out + (size_t)n * Ll * OUTC + (size_t)t0 * OUTC + inp * 384) + lane;
    f4* oind = (f4*)(out + OUT_ELEMS + (size_t)inp * NLC + ((size_t)n * Ll + t0) * Cc) + lane;
    f4* oact = (f4*)(out + OUT_ELEMS + 3 * (size_t)NLC + (size_t)inp * NLC + ((size_t)n * Ll + t0) * Cc) + lane;

    const float invL = 1.0f / (float)Ll;
#pragma unroll 4
    for (int tl = 0; tl < TILE; ++tl) {
        f4 v = p[(size_t)tl * (Cc / 4)];
        int t = t0 + tl;
        bool haspad = (t < Ll - 1);
        float rcnt = 1.0f / (float)(t + 1);
        f4 pmax, pidx, pavg, psum;
#pragma unroll
        for (int j = 0; j < 4; ++j) {
            s[j] += v[j];
            if (v[j] > m[j]) { m[j] = v[j]; mi[j] = t; }
            float cmax = m[j];
            pmax[j] = haspad ? fmaxf(cmax, 0.f) : cmax;
            pidx[j] = (float)((haspad && cmax < 0.f) ? (t - (Ll - 1)) : mi[j]);
            pavg[j] = s[j] * invL;
            psum[j] = s[j] * rcnt;
        }
        size_t ro = (size_t)tl * (OUTC / 4);
        omax[ro]            = pmax;
        omax[ro + Cc / 4]   = pavg;   // +128 floats
        omax[ro + Cc / 2]   = psum;   // +256 floats
        oind[(size_t)tl * (Cc / 4)] = pidx;
        oact[(size_t)tl * (Cc / 4)] = pmax;
    }

    // broadcast MLP columns once (via inp==0 units): 20 cols × TILE rows per unit
    if (inp == 0) {
        float* dout = out + (size_t)n * Ll * OUTC + (size_t)t0 * OUTC + 1152;
        for (int idx = lane; idx < TILE * 20; idx += 32) {
            int tl = idx / 20;
            int k = idx - tl * 20;
            dout[(size_t)tl * OUTC + k] = dvals[n * 20 + k];
        }
    }
}

extern "C" void kernel_launch(void* const* d_in, const int* in_sizes, int n_in,
                              void* d_out, int out_size, void* d_ws, size_t ws_size,
                              hipStream_t stream) {
    const float* x0  = (const float*)d_in[0];
    const float* x1  = (const float*)d_in[1];
    const float* x2  = (const float*)d_in[2];
    const float* dem = (const float*)d_in[3];
    const float* W1  = (const float*)d_in[4];
    const float* b1  = (const float*)d_in[5];
    const float* W2  = (const float*)d_in[6];
    const float* b2  = (const float*)d_in[7];
    float* out = (float*)d_out;

    char* ws = (char*)d_ws;
    float* aggMax = (float*)ws;
    int*   aggIdx = (int*)(ws + (size_t)AGG * 4);
    float* aggSum = (float*)(ws + 2 * (size_t)AGG * 4);
    float* dvals  = (float*)(ws + 3 * (size_t)AGG * 4);

    // phase 1: 6144 units, 8 units per 256-thread block
    k_agg<<<dim3(NUNITS / 8), dim3(256), 0, stream>>>(x0, x1, x2,
        (f4*)aggMax, (i4*)aggIdx, (f4*)aggSum);
    // phase 2: one thread per (inp,n,c)
    k_scan_tiles<<<dim3(48), dim3(256), 0, stream>>>(aggMax, aggIdx, aggSum);
    k_mlp<<<dim3(1), dim3(64), 0, stream>>>(dem, W1, b1, W2, b2, dvals);
    // phase 3
    k_apply<<<dim3(NUNITS / 8), dim3(256), 0, stream>>>(x0, x1, x2,
        (const f4*)aggMax, (const i4*)aggIdx, (const f4*)aggSum, dvals, out);
}

// Round 3
// 645.549 us; speedup vs baseline: 1.0780x; 1.0399x over previous
//
#include <hip/hip_runtime.h>
#include <float.h>

#define Nn 32
#define Ll 2048
#define Cc 128
#define NTILES 64
#define TILE 32                 // Ll / NTILES
#define OUTC 1172               // 3*384 + 20
#define NLC (Nn * Ll * Cc)      // 8388608
#define OUT_ELEMS ((size_t)Nn * Ll * OUTC)  // 76808192
#define NUNITS (3 * Nn * NTILES)            // 6144
#define AGG (NUNITS * Cc)                   // 786432

typedef float  f4 __attribute__((ext_vector_type(4)));
typedef int    i4 __attribute__((ext_vector_type(4)));

__device__ __forceinline__ void nts4(f4* p, f4 v) { __builtin_nontemporal_store(v, p); }
__device__ __forceinline__ void nts1(float* p, float v) { __builtin_nontemporal_store(v, p); }

// ---------------- Phase 1: per-tile aggregates (float4 lanes) ----------------
__global__ __launch_bounds__(256) void k_agg(
        const float* __restrict__ x0, const float* __restrict__ x1,
        const float* __restrict__ x2,
        f4* __restrict__ aggMax, i4* __restrict__ aggIdx, f4* __restrict__ aggSum) {
    int unit = blockIdx.x * 8 + (threadIdx.x >> 5);   // (inp, n, tile)
    int lane = threadIdx.x & 31;                      // channels lane*4..lane*4+3
    int inp = unit >> 11;                             // / (Nn*NTILES)=2048
    int rem = unit & 2047;
    int n = rem >> 6;                                 // / NTILES
    int tile = rem & 63;
    const float* x = (inp == 0) ? x0 : ((inp == 1) ? x1 : x2);
    int t0 = tile * TILE;
    const f4* p = (const f4*)(x + ((size_t)n * Ll + t0) * Cc) + lane;

    f4 m = { -FLT_MAX, -FLT_MAX, -FLT_MAX, -FLT_MAX };
    i4 mi = { 0, 0, 0, 0 };
    f4 s = { 0.f, 0.f, 0.f, 0.f };
#pragma unroll 4
    for (int tl = 0; tl < TILE; ++tl) {
        f4 v = p[(size_t)tl * (Cc / 4)];
        int t = t0 + tl;
#pragma unroll
        for (int j = 0; j < 4; ++j) {
            s[j] += v[j];
            if (v[j] > m[j]) { m[j] = v[j]; mi[j] = t; }   // strict >: earlier wins ties
        }
    }
    int o = unit * (Cc / 4) + lane;
    aggMax[o] = m; aggIdx[o] = mi; aggSum[o] = s;   // re-read by scan: keep cached
}

// ------- Phase 2 (fused): blocks 0..47 exclusive-scan tile aggregates; block 48 MLP -------
__global__ __launch_bounds__(256) void k_scan_mlp(
        float* __restrict__ aggMax, int* __restrict__ aggIdx, float* __restrict__ aggSum,
        const float* __restrict__ dem, const float* __restrict__ W1,
        const float* __restrict__ b1, const float* __restrict__ W2,
        const float* __restrict__ b2, float* __restrict__ dvals) {
    if (blockIdx.x < 48) {
        int tid = blockIdx.x * 256 + threadIdx.x;      // 0..12287 : (inp, n, c)
        int inp = tid / (Nn * Cc);
        int rem = tid - inp * (Nn * Cc);
        int n = rem >> 7;
        int c = rem & 127;
        int base = ((inp * Nn + n) * NTILES) * Cc + c;

        float m = -FLT_MAX; int mi = 0; float s = 0.f;
#pragma unroll 4
        for (int j = 0; j < NTILES; ++j) {
            int o = base + j * Cc;
            float am = aggMax[o]; int ai = aggIdx[o]; float as = aggSum[o];
            aggMax[o] = m; aggIdx[o] = mi; aggSum[o] = s;   // exclusive prefix
            if (am > m) { m = am; mi = ai; }
            s += as;
        }
    } else {
        int n = threadIdx.x;
        if (n >= Nn) return;
        float h[40];
        float de[8];
#pragma unroll
        for (int k = 0; k < 8; ++k) de[k] = dem[n * 8 + k];
#pragma unroll
        for (int j = 0; j < 40; ++j) {
            float s = b1[j];
#pragma unroll
            for (int k = 0; k < 8; ++k) s += de[k] * W1[k * 40 + j];
            h[j] = fmaxf(s, 0.f);
        }
#pragma unroll
        for (int o = 0; o < 20; ++o) {
            float s = b2[o];
#pragma unroll
            for (int j = 0; j < 40; ++j) s += h[j] * W2[j * 20 + o];
            dvals[n * 20 + o] = fmaxf(s, 0.f);
        }
    }
}

// ---------------- Phase 3: rescan with carry, nontemporal float4 writes ----------------
__global__ __launch_bounds__(256) void k_apply(
        const float* __restrict__ x0, const float* __restrict__ x1,
        const float* __restrict__ x2,
        const f4* __restrict__ aggMax, const i4* __restrict__ aggIdx,
        const f4* __restrict__ aggSum, const float* __restrict__ dvals,
        float* __restrict__ out) {
    int unit = blockIdx.x * 8 + (threadIdx.x >> 5);
    int lane = threadIdx.x & 31;
    int inp = unit >> 11;
    int rem = unit & 2047;
    int n = rem >> 6;
    int tile = rem & 63;
    const float* x = (inp == 0) ? x0 : ((inp == 1) ? x1 : x2);
    int t0 = tile * TILE;

    int o = unit * (Cc / 4) + lane;
    f4 m = aggMax[o]; i4 mi = aggIdx[o]; f4 s = aggSum[o];   // carry-in (exclusive)

    // MLP columns for this n, cached in registers (only inp==0 units broadcast them)
    float dv = 0.f;
    if (inp == 0 && lane < 20) dv = dvals[n * 20 + lane];

    const f4* p = (const f4*)(x + ((size_t)n * Ll + t0) * Cc) + lane;
    // out row layout: inp*384 + {0:pmax, 128:pavg, 256:psum}, then 1152..1171 = d
    f4* omax = (f4*)(out + (size_t)n * Ll * OUTC + (size_t)t0 * OUTC + inp * 384) + lane;
    f4* oind = (f4*)(out + OUT_ELEMS + (size_t)inp * NLC + ((size_t)n * Ll + t0) * Cc) + lane;
    f4* oact = (f4*)(out + OUT_ELEMS + 3 * (size_t)NLC + (size_t)inp * NLC + ((size_t)n * Ll + t0) * Cc) + lane;
    float* dout = out + (size_t)n * Ll * OUTC + (size_t)t0 * OUTC + 1152 + (lane < 20 ? lane : 0);

    const float invL = 1.0f / (float)Ll;
#pragma unroll 4
    for (int tl = 0; tl < TILE; ++tl) {
        f4 v = p[(size_t)tl * (Cc / 4)];
        int t = t0 + tl;
        bool haspad = (t < Ll - 1);
        float rcnt = __builtin_amdgcn_rcpf((float)(t + 1));   // ~1 ulp, well within threshold
        f4 pmax, pidx, pavg, psum;
#pragma unroll
        for (int j = 0; j < 4; ++j) {
            s[j] += v[j];
            if (v[j] > m[j]) { m[j] = v[j]; mi[j] = t; }
            float cmax = m[j];
            pmax[j] = haspad ? fmaxf(cmax, 0.f) : cmax;
            pidx[j] = (float)((haspad && cmax < 0.f) ? (t - (Ll - 1)) : mi[j]);
            pavg[j] = s[j] * invL;
            psum[j] = s[j] * rcnt;
        }
        size_t ro = (size_t)tl * (OUTC / 4);
        nts4(&omax[ro],          pmax);
        nts4(&omax[ro + Cc / 4], pavg);   // +128 floats
        nts4(&omax[ro + Cc / 2], psum);   // +256 floats
        nts4(&oind[(size_t)tl * (Cc / 4)], pidx);
        nts4(&oact[(size_t)tl * (Cc / 4)], pmax);
        if (inp == 0 && lane < 20)
            nts1(&dout[(size_t)tl * OUTC], dv);   // coalesced 80 B row segment
    }
}

extern "C" void kernel_launch(void* const* d_in, const int* in_sizes, int n_in,
                              void* d_out, int out_size, void* d_ws, size_t ws_size,
                              hipStream_t stream) {
    const float* x0  = (const float*)d_in[0];
    const float* x1  = (const float*)d_in[1];
    const float* x2  = (const float*)d_in[2];
    const float* dem = (const float*)d_in[3];
    const float* W1  = (const float*)d_in[4];
    const float* b1  = (const float*)d_in[5];
    const float* W2  = (const float*)d_in[6];
    const float* b2  = (const float*)d_in[7];
    float* out = (float*)d_out;

    char* ws = (char*)d_ws;
    float* aggMax = (float*)ws;
    int*   aggIdx = (int*)(ws + (size_t)AGG * 4);
    float* aggSum = (float*)(ws + 2 * (size_t)AGG * 4);
    float* dvals  = (float*)(ws + 3 * (size_t)AGG * 4);

    k_agg<<<dim3(NUNITS / 8), dim3(256), 0, stream>>>(x0, x1, x2,
        (f4*)aggMax, (i4*)aggIdx, (f4*)aggSum);
    k_scan_mlp<<<dim3(49), dim3(256), 0, stream>>>(aggMax, aggIdx, aggSum,
        dem, W1, b1, W2, b2, dvals);
    k_apply<<<dim3(NUNITS / 8), dim3(256), 0, stream>>>(x0, x1, x2,
        (const f4*)aggMax, (const i4*)aggIdx, (const f4*)aggSum, dvals, out);
}